// Round 1
// baseline (982.643 us; speedup 1.0000x reference)
//
#include <hip/hip_runtime.h>
#include <hip/hip_bf16.h>
#include <cstddef>

// Problem constants
#define Bv 4
#define Nv 1024
#define DM 512
#define Hh 8
#define DHv 64

// ---------------------------------------------------------------------------
// LayerNorm: one block per row of 512
// ---------------------------------------------------------------------------
__global__ __launch_bounds__(256) void ln_kernel(
    const float* __restrict__ X, const float* __restrict__ g,
    const float* __restrict__ bb, float* __restrict__ Y)
{
    __shared__ float red[8];
    int row = blockIdx.x, tid = threadIdx.x;
    const float* x = X + (size_t)row * DM;
    float v0 = x[tid], v1 = x[tid + 256];
    float s = v0 + v1, ss = v0 * v0 + v1 * v1;
#pragma unroll
    for (int o = 32; o > 0; o >>= 1) {
        s += __shfl_xor(s, o);
        ss += __shfl_xor(ss, o);
    }
    int lane = tid & 63, wid = tid >> 6;
    if (lane == 0) { red[wid] = s; red[4 + wid] = ss; }
    __syncthreads();
    float S = red[0] + red[1] + red[2] + red[3];
    float SS = red[4] + red[5] + red[6] + red[7];
    float mean = S * (1.f / DM);
    float var = SS * (1.f / DM) - mean * mean;
    float rstd = rsqrtf(var + 1e-5f);
    float* y = Y + (size_t)row * DM;
    y[tid]       = (v0 - mean) * rstd * g[tid]       + bb[tid];
    y[tid + 256] = (v1 - mean) * rstd * g[tid + 256] + bb[tid + 256];
}

// ---------------------------------------------------------------------------
// Generic fp32 NT GEMM: C[M,Nc] = A[M,K] @ Bw[Nc,K]^T  (+ epilogues)
// EPI 0: qkv scatter (+bias)  -> C=V, C2=Q, C3=K  laid out (b,h,n,d)
// EPI 1: + resid              -> C (Z2 = attn_out + Z)
// EPI 2: relu(+bias)          -> C (MLP hidden)
// EPI 3: + bias + resid       -> C (final out)
// ---------------------------------------------------------------------------
template <int EPI>
__global__ __launch_bounds__(256) void gemm_nt(
    const float* __restrict__ A, const float* __restrict__ Bw,
    const float* __restrict__ bias, const float* __restrict__ resid,
    float* __restrict__ C, float* __restrict__ C2, float* __restrict__ C3,
    int M, int Nc, int K)
{
    __shared__ float As[16][68];
    __shared__ float Bs[16][68];
    int tid = threadIdx.x;
    int tx = tid & 15, ty = tid >> 4;
    int bn = blockIdx.x * 64, bm = blockIdx.y * 64;
    float acc[4][4] = {};

    for (int k0 = 0; k0 < K; k0 += 16) {
        __syncthreads();
#pragma unroll
        for (int i = 0; i < 4; i++) {
            int l = tid + i * 256;
            int r = l >> 4, c = l & 15;
            As[c][r] = A[(size_t)(bm + r) * K + k0 + c];
            Bs[c][r] = Bw[(size_t)(bn + r) * K + k0 + c];
        }
        __syncthreads();
#pragma unroll
        for (int kk = 0; kk < 16; kk++) {
            float4 a = *(const float4*)&As[kk][ty * 4];
            float4 b = *(const float4*)&Bs[kk][tx * 4];
            acc[0][0] += a.x * b.x; acc[0][1] += a.x * b.y; acc[0][2] += a.x * b.z; acc[0][3] += a.x * b.w;
            acc[1][0] += a.y * b.x; acc[1][1] += a.y * b.y; acc[1][2] += a.y * b.z; acc[1][3] += a.y * b.w;
            acc[2][0] += a.z * b.x; acc[2][1] += a.z * b.y; acc[2][2] += a.z * b.z; acc[2][3] += a.z * b.w;
            acc[3][0] += a.w * b.x; acc[3][1] += a.w * b.y; acc[3][2] += a.w * b.z; acc[3][3] += a.w * b.w;
        }
    }

#pragma unroll
    for (int i = 0; i < 4; i++) {
        int m = bm + ty * 4 + i;
#pragma unroll
        for (int j = 0; j < 4; j++) {
            int cidx = bn + tx * 4 + j;
            float v = acc[i][j];
            if (EPI == 0) {
                v += bias[cidx];
                int hh = cidx / 192;
                int rr = cidx - hh * 192;
                int part = rr >> 6, dd = rr & 63;
                int bI = m >> 10, nI = m & 1023;
                float* dst = (part == 0) ? C : ((part == 1) ? C2 : C3);
                dst[(((size_t)(bI * Hh + hh)) * Nv + nI) * DHv + dd] = v;
            } else if (EPI == 1) {
                C[(size_t)m * Nc + cidx] = v + resid[(size_t)m * Nc + cidx];
            } else if (EPI == 2) {
                v += bias[cidx];
                C[(size_t)m * Nc + cidx] = v > 0.f ? v : 0.f;
            } else {
                C[(size_t)m * Nc + cidx] = v + bias[cidx] + resid[(size_t)m * Nc + cidx];
            }
        }
    }
}

// ---------------------------------------------------------------------------
// Attention: one block handles 8 query rows for one (b,h).
// scores = QK^T/8 + new_mask - gamma*D ; softmax over m ; * mask ; @ V ;
// leaky_relu fused into the store.
// ---------------------------------------------------------------------------
#define NB 8

__global__ __launch_bounds__(256) void attn_kernel(
    const float* __restrict__ Qb, const float* __restrict__ Kb,
    const float* __restrict__ Vb, const float* __restrict__ Dm,
    const float* __restrict__ nmask, const float* __restrict__ mask,
    const float* __restrict__ gamma, float* __restrict__ attn_out)
{
    __shared__ float qs[NB][68];
    __shared__ float Ks[64][68];   // reused for V in phase 3
    __shared__ float sc[NB][1025];

    int tid = threadIdx.x;
    int n0 = blockIdx.x * NB;
    int h = blockIdx.y, b = blockIdx.z;
    const size_t bh = (size_t)(b * Hh + h) * Nv * DHv;
    const float* Kbase = Kb + bh;
    const float* Qbase = Qb + bh;
    const float* Vbase = Vb + bh;

    for (int l = tid; l < NB * 64; l += 256) {
        int r = l >> 6, d = l & 63;
        qs[r][d] = Qbase[(size_t)(n0 + r) * DHv + d];
    }
    float gam = gamma[0];

    // ---- phase 1: scores (QK^T only; bias terms added in softmax phase) ----
    for (int c = 0; c < 16; c++) {
        int m0 = c * 64;
        __syncthreads();
        for (int l = tid; l < 64 * 64; l += 256) {
            int mm = l >> 6, d = l & 63;
            Ks[mm][d] = Kbase[(size_t)(m0 + mm) * DHv + d];
        }
        __syncthreads();
#pragma unroll
        for (int p = 0; p < 2; p++) {
            int pr = tid + p * 256;
            int mm = pr >> 3, r = pr & 7;
            const float4* kp = (const float4*)Ks[mm];
            const float4* qp = (const float4*)qs[r];
            float s = 0.f;
#pragma unroll
            for (int d4 = 0; d4 < 16; d4++) {
                float4 kk = kp[d4], qq = qp[d4];
                s += kk.x * qq.x + kk.y * qq.y + kk.z * qq.z + kk.w * qq.w;
            }
            sc[r][m0 + mm] = s;
        }
    }
    __syncthreads();

    // ---- phase 2: softmax per row; wave w owns rows w and w+4 ----
    int lane = tid & 63, wid = tid >> 6;
#pragma unroll
    for (int rr = 0; rr < 2; rr++) {
        int r = wid + rr * 4;
        int n = n0 + r;
        const float* Dr = Dm + ((size_t)b * Nv + n) * Nv;
        const float* Nr = nmask + ((size_t)b * Nv + n) * Nv;
        const float* Mr = mask + ((size_t)b * Nv + n) * Nv;
        float vals[16];
        float mx = -INFINITY;
#pragma unroll
        for (int j = 0; j < 16; j++) {
            int i = lane + j * 64;
            float s = sc[r][i] * 0.125f + Nr[i] - gam * Dr[i];
            vals[j] = s;
            mx = fmaxf(mx, s);
        }
#pragma unroll
        for (int o = 32; o > 0; o >>= 1) mx = fmaxf(mx, __shfl_xor(mx, o));
        float sum = 0.f;
#pragma unroll
        for (int j = 0; j < 16; j++) {
            float e = __expf(vals[j] - mx);
            vals[j] = e;
            sum += e;
        }
#pragma unroll
        for (int o = 32; o > 0; o >>= 1) sum += __shfl_xor(sum, o);
        float inv = 1.f / sum;
#pragma unroll
        for (int j = 0; j < 16; j++) {
            int i = lane + j * 64;
            sc[r][i] = vals[j] * inv * Mr[i];
        }
    }

    // ---- phase 3: PV ; thread owns (r0,d) and (r0+4,d) ----
    float acc0 = 0.f, acc1 = 0.f;
    int d = tid & 63, r0 = tid >> 6;
    for (int c = 0; c < 16; c++) {
        int m0 = c * 64;
        __syncthreads();
        for (int l = tid; l < 64 * 64; l += 256) {
            int mm = l >> 6, dd = l & 63;
            Ks[mm][dd] = Vbase[(size_t)(m0 + mm) * DHv + dd];
        }
        __syncthreads();
#pragma unroll 8
        for (int mm = 0; mm < 64; mm++) {
            float vv = Ks[mm][d];
            acc0 += sc[r0][m0 + mm] * vv;
            acc1 += sc[r0 + 4][m0 + mm] * vv;
        }
    }
    float o0 = acc0 > 0.f ? acc0 : 0.01f * acc0;
    float o1 = acc1 > 0.f ? acc1 : 0.01f * acc1;
    attn_out[((size_t)b * Nv + n0 + r0) * DM + h * DHv + d] = o0;
    attn_out[((size_t)b * Nv + n0 + r0 + 4) * DM + h * DHv + d] = o1;
}

// ---------------------------------------------------------------------------
extern "C" void kernel_launch(void* const* d_in, const int* in_sizes, int n_in,
                              void* d_out, int out_size, void* d_ws, size_t ws_size,
                              hipStream_t stream)
{
    const float* Z     = (const float*)d_in[0];
    const float* D     = (const float*)d_in[1];
    const float* nmsk  = (const float*)d_in[2];
    const float* msk   = (const float*)d_in[3];
    const float* Wqkv  = (const float*)d_in[4];
    const float* bqkv  = (const float*)d_in[5];
    const float* Wo    = (const float*)d_in[6];
    const float* g1    = (const float*)d_in[7];
    const float* b1    = (const float*)d_in[8];
    const float* g2    = (const float*)d_in[9];
    const float* b2    = (const float*)d_in[10];
    const float* Wp1   = (const float*)d_in[11];
    const float* bp1   = (const float*)d_in[12];
    const float* Wp2   = (const float*)d_in[13];
    const float* bp2   = (const float*)d_in[14];
    const float* gamma = (const float*)d_in[15];
    float* out = (float*)d_out;
    float* ws  = (float*)d_ws;

    const size_t TOK = (size_t)Bv * Nv;          // 4096
    const size_t SEG = TOK * DM;                 // 2M floats

    // workspace layout (12M floats = 48 MB):
    //  [0,2M):   Zn -> attn_l -> Zn2
    //  [2M,10M): Q | K | V  -> later reused as MLP hidden H (8M)
    //  [10M,12M): Z2
    float* r0  = ws;                // Zn / attn_l / Zn2
    float* Qb  = ws + SEG;          // 2M..4M
    float* Kb  = ws + 2 * SEG;      // 4M..6M
    float* Vb  = ws + 3 * SEG;      // 6M..8M
    float* Hb  = ws + SEG;          // 2M..10M (overlays Q,K,V after attention)
    float* Z2  = ws + 5 * SEG;      // 10M..12M

    // 1) Zn = LN(Z)
    ln_kernel<<<dim3(TOK), 256, 0, stream>>>(Z, g1, b1, r0);

    // 2) QKV GEMM, scatter to V,Q,K (b,h,n,d)
    gemm_nt<0><<<dim3(1536 / 64, TOK / 64), 256, 0, stream>>>(
        r0, Wqkv, bqkv, nullptr, Vb, Qb, Kb, (int)TOK, 1536, DM);

    // 3) attention -> leaky_relu(attn) into r0
    attn_kernel<<<dim3(Nv / NB, Hh, Bv), 256, 0, stream>>>(
        Qb, Kb, Vb, D, nmsk, msk, gamma, r0);

    // 4) Z2 = attn_l @ Wo^T + Z
    gemm_nt<1><<<dim3(DM / 64, TOK / 64), 256, 0, stream>>>(
        r0, Wo, nullptr, Z, Z2, nullptr, nullptr, (int)TOK, DM, DM);

    // 5) Zn2 = LN(Z2) into r0
    ln_kernel<<<dim3(TOK), 256, 0, stream>>>(Z2, g2, b2, r0);

    // 6) H = relu(Zn2 @ Wp1^T + bp1)
    gemm_nt<2><<<dim3(2048 / 64, TOK / 64), 256, 0, stream>>>(
        r0, Wp1, bp1, nullptr, Hb, nullptr, nullptr, (int)TOK, 2048, DM);

    // 7) out = H @ Wp2^T + bp2 + Z2
    gemm_nt<3><<<dim3(DM / 64, TOK / 64), 256, 0, stream>>>(
        Hb, Wp2, bp2, Z2, out, nullptr, nullptr, (int)TOK, DM, 2048);
}

// Round 2
// 307.331 us; speedup vs baseline: 3.1973x; 3.1973x over previous
//
#include <hip/hip_runtime.h>
#include <hip/hip_bf16.h>
#include <cstddef>
#include <cstdint>

#define Bv 4
#define Nv 1024
#define DM 512
#define Hh 8
#define DHv 64
#define TOKc 4096

typedef __attribute__((ext_vector_type(4))) float f32x4;
typedef __attribute__((ext_vector_type(8))) short s16x8;

__device__ __forceinline__ uint32_t f2bf_bits(float f) {
    uint32_t x = __float_as_uint(f);
    return (x + 0x7FFFu + ((x >> 16) & 1u)) >> 16;
}
__device__ __forceinline__ short f2bf(float f) { return (short)f2bf_bits(f); }

__device__ __forceinline__ void g2lds16(const void* g, void* l) {
    __builtin_amdgcn_global_load_lds(
        (const __attribute__((address_space(1))) void*)g,
        (__attribute__((address_space(3))) void*)l, 16, 0, 0);
}

// ---------------------------------------------------------------------------
// fp32 -> bf16 convert (weights)
// ---------------------------------------------------------------------------
__global__ __launch_bounds__(256) void conv_bf16(
    const float* __restrict__ s, short* __restrict__ d, int n)
{
    int i = (blockIdx.x * 256 + threadIdx.x) * 4;
    if (i < n) {
        float4 v = *(const float4*)&s[i];
        d[i + 0] = f2bf(v.x); d[i + 1] = f2bf(v.y);
        d[i + 2] = f2bf(v.z); d[i + 3] = f2bf(v.w);
    }
}

// ---------------------------------------------------------------------------
// pack bias = new_mask - gamma*D (lo bf16) and mask (hi bf16) into u32
// ---------------------------------------------------------------------------
__global__ __launch_bounds__(256) void prep_bm(
    const float* __restrict__ Dm, const float* __restrict__ nm,
    const float* __restrict__ mk, const float* __restrict__ gamma,
    uint32_t* __restrict__ out)
{
    int i = (blockIdx.x * 256 + threadIdx.x) * 4;
    float g = gamma[0];
    float4 d = *(const float4*)&Dm[i];
    float4 n = *(const float4*)&nm[i];
    float4 m = *(const float4*)&mk[i];
    uint4 o;
    o.x = f2bf_bits(n.x - g * d.x) | (f2bf_bits(m.x) << 16);
    o.y = f2bf_bits(n.y - g * d.y) | (f2bf_bits(m.y) << 16);
    o.z = f2bf_bits(n.z - g * d.z) | (f2bf_bits(m.z) << 16);
    o.w = f2bf_bits(n.w - g * d.w) | (f2bf_bits(m.w) << 16);
    *(uint4*)&out[i] = o;
}

// ---------------------------------------------------------------------------
// LayerNorm -> bf16 out
// ---------------------------------------------------------------------------
__global__ __launch_bounds__(256) void ln_kernel(
    const float* __restrict__ X, const float* __restrict__ g,
    const float* __restrict__ bb, short* __restrict__ Y)
{
    __shared__ float red[8];
    int row = blockIdx.x, tid = threadIdx.x;
    const float* x = X + (size_t)row * DM;
    float v0 = x[tid], v1 = x[tid + 256];
    float s = v0 + v1, ss = v0 * v0 + v1 * v1;
#pragma unroll
    for (int o = 32; o > 0; o >>= 1) {
        s += __shfl_xor(s, o);
        ss += __shfl_xor(ss, o);
    }
    int lane = tid & 63, wid = tid >> 6;
    if (lane == 0) { red[wid] = s; red[4 + wid] = ss; }
    __syncthreads();
    float S = red[0] + red[1] + red[2] + red[3];
    float SS = red[4] + red[5] + red[6] + red[7];
    float mean = S * (1.f / DM);
    float var = SS * (1.f / DM) - mean * mean;
    float rstd = rsqrtf(var + 1e-5f);
    short* y = Y + (size_t)row * DM;
    y[tid]       = f2bf((v0 - mean) * rstd * g[tid]       + bb[tid]);
    y[tid + 256] = f2bf((v1 - mean) * rstd * g[tid + 256] + bb[tid + 256]);
}

// ---------------------------------------------------------------------------
// bf16 MFMA NT GEMM: C[M,N] = A[M,K] @ Bw[N,K]^T, 128x128 tile, BK=32
// EPI 0: +bias, scatter qkv -> Vt(b,h,d,n) / Q(b,h,n,d) / K(b,h,n,d)  bf16
// EPI 1: + resid -> fp32
// EPI 2: relu(+bias) -> bf16
// EPI 3: + bias + resid -> fp32
// ---------------------------------------------------------------------------
template <int EPI>
__global__ __launch_bounds__(256) void gemm_bf16(
    const short* __restrict__ A, const short* __restrict__ Bw,
    const float* __restrict__ bias, const float* __restrict__ resid,
    void* __restrict__ C0, short* __restrict__ C2, short* __restrict__ C3,
    int M, int N, int K)
{
    __shared__ short As[128 * 32];
    __shared__ short Bs[128 * 32];
    int tid = threadIdx.x;
    int lane = tid & 63, wave = tid >> 6;
    int bm = blockIdx.y * 128, bn = blockIdx.x * 128;
    int wm = (wave >> 1) * 64, wn = (wave & 1) * 64;
    int n_lo = lane & 15, quad = lane >> 4;

    f32x4 acc[4][4] = {};

    int lrow = lane >> 2, lchunk = (lane & 3) * 8;
    const short* Ag = A + (size_t)(bm + wave * 32 + lrow) * K + lchunk;
    const short* Bg = Bw + (size_t)(bn + wave * 32 + lrow) * K + lchunk;
    short* AsW0 = &As[(wave * 32) * 32];
    short* AsW1 = &As[(wave * 32 + 16) * 32];
    short* BsW0 = &Bs[(wave * 32) * 32];
    short* BsW1 = &Bs[(wave * 32 + 16) * 32];

    for (int k0 = 0; k0 < K; k0 += 32) {
        __syncthreads();
        g2lds16(Ag + k0, AsW0);
        g2lds16(Ag + (size_t)16 * K + k0, AsW1);
        g2lds16(Bg + k0, BsW0);
        g2lds16(Bg + (size_t)16 * K + k0, BsW1);
        __syncthreads();
        s16x8 af[4], bf[4];
#pragma unroll
        for (int i = 0; i < 4; i++)
            af[i] = *(const s16x8*)&As[(wm + i * 16 + n_lo) * 32 + quad * 8];
#pragma unroll
        for (int j = 0; j < 4; j++)
            bf[j] = *(const s16x8*)&Bs[(wn + j * 16 + n_lo) * 32 + quad * 8];
#pragma unroll
        for (int i = 0; i < 4; i++)
#pragma unroll
            for (int j = 0; j < 4; j++)
                acc[i][j] = __builtin_amdgcn_mfma_f32_16x16x32_bf16(
                    af[i], bf[j], acc[i][j], 0, 0, 0);
    }

#pragma unroll
    for (int i = 0; i < 4; i++) {
#pragma unroll
        for (int j = 0; j < 4; j++) {
            int col = bn + wn + j * 16 + n_lo;
#pragma unroll
            for (int r = 0; r < 4; r++) {
                int m = bm + wm + i * 16 + quad * 4 + r;
                float v = acc[i][j][r];
                if (EPI == 0) {
                    v += bias[col];
                    int hh = col / 192;
                    int rr = col - hh * 192;
                    int part = rr >> 6, dd = rr & 63;
                    int bI = m >> 10, nI = m & 1023;
                    if (part == 0)       // V -> Vt[b][h][d][n]
                        ((short*)C0)[((size_t)((bI * Hh + hh) * DHv + dd)) * Nv + nI] = f2bf(v);
                    else if (part == 1)  // Q -> [b][h][n][d]
                        C2[((size_t)((bI * Hh + hh) * Nv + nI)) * DHv + dd] = f2bf(v);
                    else                 // K -> [b][h][n][d]
                        C3[((size_t)((bI * Hh + hh) * Nv + nI)) * DHv + dd] = f2bf(v);
                } else if (EPI == 1) {
                    ((float*)C0)[(size_t)m * N + col] = v + resid[(size_t)m * N + col];
                } else if (EPI == 2) {
                    v += bias[col];
                    ((short*)C0)[(size_t)m * N + col] = f2bf(v > 0.f ? v : 0.f);
                } else {
                    ((float*)C0)[(size_t)m * N + col] =
                        v + bias[col] + resid[(size_t)m * N + col];
                }
            }
        }
    }
}

// ---------------------------------------------------------------------------
// Flash attention: wave = one head x 16 query rows; online softmax; MFMA.
// S = Q@K^T/8 + bias ; P = exp(S-m)*mask ; O = P@V / l ; leaky_relu; bf16 out
// ---------------------------------------------------------------------------
__global__ __launch_bounds__(256) void attn_mfma(
    const short* __restrict__ Q, const short* __restrict__ K,
    const short* __restrict__ Vt, const uint32_t* __restrict__ Bm,
    short* __restrict__ attn_l)
{
    __shared__ short Pl[4][16][40];
    int tid = threadIdx.x, lane = tid & 63, wave = tid >> 6;
    int n_lo = lane & 15, quad = lane >> 4;
    int q0 = blockIdx.x * 16, b = blockIdx.y, h = blockIdx.z * 4 + wave;

    const short* Qp = Q + ((size_t)((b * Hh + h) * Nv + q0)) * DHv;
    const short* Kp = K + ((size_t)((b * Hh + h) * Nv)) * DHv;
    const short* Vp = Vt + ((size_t)((b * Hh + h) * DHv)) * Nv;
    const uint32_t* Bp = Bm + ((size_t)(b * Nv + q0)) * Nv;

    s16x8 a0 = *(const s16x8*)&Qp[n_lo * DHv + quad * 8];
    s16x8 a1 = *(const s16x8*)&Qp[n_lo * DHv + 32 + quad * 8];

    f32x4 O[4] = {};
    float mo[4] = {-1e30f, -1e30f, -1e30f, -1e30f};
    float l[4] = {0.f, 0.f, 0.f, 0.f};

    for (int it = 0; it < 32; ++it) {
        int key0 = it * 32;
        s16x8 k0a = *(const s16x8*)&Kp[(size_t)(key0 + n_lo) * DHv + quad * 8];
        s16x8 k0b = *(const s16x8*)&Kp[(size_t)(key0 + n_lo) * DHv + 32 + quad * 8];
        s16x8 k1a = *(const s16x8*)&Kp[(size_t)(key0 + 16 + n_lo) * DHv + quad * 8];
        s16x8 k1b = *(const s16x8*)&Kp[(size_t)(key0 + 16 + n_lo) * DHv + 32 + quad * 8];
        f32x4 z = {0.f, 0.f, 0.f, 0.f};
        f32x4 s0 = __builtin_amdgcn_mfma_f32_16x16x32_bf16(
            a1, k0b, __builtin_amdgcn_mfma_f32_16x16x32_bf16(a0, k0a, z, 0, 0, 0), 0, 0, 0);
        f32x4 s1 = __builtin_amdgcn_mfma_f32_16x16x32_bf16(
            a1, k1b, __builtin_amdgcn_mfma_f32_16x16x32_bf16(a0, k1a, z, 0, 0, 0), 0, 0, 0);

        float mk0[4], mk1[4], mx[4];
#pragma unroll
        for (int i = 0; i < 4; i++) {
            uint32_t u0 = Bp[(size_t)(quad * 4 + i) * Nv + key0 + n_lo];
            uint32_t u1 = Bp[(size_t)(quad * 4 + i) * Nv + key0 + 16 + n_lo];
            s0[i] = s0[i] * 0.125f + __uint_as_float(u0 << 16);
            s1[i] = s1[i] * 0.125f + __uint_as_float(u1 << 16);
            mk0[i] = __uint_as_float(u0 & 0xFFFF0000u);
            mk1[i] = __uint_as_float(u1 & 0xFFFF0000u);
            mx[i] = fmaxf(s0[i], s1[i]);
        }
#pragma unroll
        for (int off = 1; off < 16; off <<= 1)
#pragma unroll
            for (int i = 0; i < 4; i++)
                mx[i] = fmaxf(mx[i], __shfl_xor(mx[i], off));

        float al[4], ls[4];
#pragma unroll
        for (int i = 0; i < 4; i++) {
            float mn = fmaxf(mo[i], mx[i]);
            al[i] = __expf(mo[i] - mn);
            mo[i] = mn;
            s0[i] = __expf(s0[i] - mn);
            s1[i] = __expf(s1[i] - mn);
            ls[i] = s0[i] + s1[i];
        }
#pragma unroll
        for (int off = 1; off < 16; off <<= 1)
#pragma unroll
            for (int i = 0; i < 4; i++)
                ls[i] += __shfl_xor(ls[i], off);
#pragma unroll
        for (int i = 0; i < 4; i++) {
            l[i] = l[i] * al[i] + ls[i];
            Pl[wave][quad * 4 + i][n_lo]      = f2bf(s0[i] * mk0[i]);
            Pl[wave][quad * 4 + i][16 + n_lo] = f2bf(s1[i] * mk1[i]);
        }
#pragma unroll
        for (int t = 0; t < 4; t++)
#pragma unroll
            for (int i = 0; i < 4; i++) O[t][i] *= al[i];

        s16x8 pa = *(const s16x8*)&Pl[wave][n_lo][quad * 8];
#pragma unroll
        for (int t = 0; t < 4; t++) {
            s16x8 vb = *(const s16x8*)&Vp[(size_t)(t * 16 + n_lo) * Nv + key0 + quad * 8];
            O[t] = __builtin_amdgcn_mfma_f32_16x16x32_bf16(pa, vb, O[t], 0, 0, 0);
        }
    }

    float inv[4];
#pragma unroll
    for (int i = 0; i < 4; i++) inv[i] = 1.f / l[i];
#pragma unroll
    for (int t = 0; t < 4; t++)
#pragma unroll
        for (int i = 0; i < 4; i++) {
            float o = O[t][i] * inv[i];
            o = o > 0.f ? o : 0.01f * o;
            attn_l[((size_t)(b * Nv + q0 + quad * 4 + i)) * DM + h * DHv + t * 16 + n_lo] = f2bf(o);
        }
}

// ---------------------------------------------------------------------------
extern "C" void kernel_launch(void* const* d_in, const int* in_sizes, int n_in,
                              void* d_out, int out_size, void* d_ws, size_t ws_size,
                              hipStream_t stream)
{
    const float* Z     = (const float*)d_in[0];
    const float* D     = (const float*)d_in[1];
    const float* nmsk  = (const float*)d_in[2];
    const float* msk   = (const float*)d_in[3];
    const float* Wqkv  = (const float*)d_in[4];
    const float* bqkv  = (const float*)d_in[5];
    const float* Wo    = (const float*)d_in[6];
    const float* g1    = (const float*)d_in[7];
    const float* b1    = (const float*)d_in[8];
    const float* g2    = (const float*)d_in[9];
    const float* b2    = (const float*)d_in[10];
    const float* Wp1   = (const float*)d_in[11];
    const float* bp1   = (const float*)d_in[12];
    const float* Wp2   = (const float*)d_in[13];
    const float* bp2   = (const float*)d_in[14];
    const float* gamma = (const float*)d_in[15];
    float* out = (float*)d_out;
    char* w = (char*)d_ws;

    const size_t MB = 1048576;
    short*    WqkvB = (short*)(w);                 // 1.5 MB
    short*    WoB   = (short*)(w + 1572864);       // 0.5 MB
    short*    Wp1B  = (short*)(w + 2 * MB);        // 2 MB
    short*    Wp2B  = (short*)(w + 4 * MB);        // 2 MB
    float*    Z2    = (float*)(w + 6 * MB);        // 8 MB   [6,14)
    uint32_t* Bm    = (uint32_t*)(w + 14 * MB);    // 16 MB  [14,30) dead after attn
    short*    Zn    = (short*)(w + 30 * MB);       // 4 MB   [30,34) dead after QKV
    short*    Qb    = (short*)(w + 34 * MB);       // 4 MB
    short*    Kb    = (short*)(w + 38 * MB);       // 4 MB
    short*    VtB   = (short*)(w + 42 * MB);       // 4 MB   [34,46) dead after attn
    short*    AtnL  = (short*)(w + 30 * MB);       // reuse Zn slot
    short*    Zn2   = (short*)(w + 14 * MB);       // reuse Bm slot
    short*    Hb    = (short*)(w + 18 * MB);       // 16 MB  [18,34)

    // weights -> bf16
    conv_bf16<<<768, 256, 0, stream>>>(Wqkv, WqkvB, 1536 * 512);
    conv_bf16<<<256, 256, 0, stream>>>(Wo, WoB, 512 * 512);
    conv_bf16<<<1024, 256, 0, stream>>>(Wp1, Wp1B, 2048 * 512);
    conv_bf16<<<1024, 256, 0, stream>>>(Wp2, Wp2B, 512 * 2048);
    // bias/mask pack
    prep_bm<<<4096, 256, 0, stream>>>(D, nmsk, msk, gamma, Bm);
    // LN1
    ln_kernel<<<TOKc, 256, 0, stream>>>(Z, g1, b1, Zn);
    // QKV
    gemm_bf16<0><<<dim3(12, 32), 256, 0, stream>>>(
        Zn, WqkvB, bqkv, nullptr, VtB, Qb, Kb, TOKc, 1536, 512);
    // attention
    attn_mfma<<<dim3(64, 4, 2), 256, 0, stream>>>(Qb, Kb, VtB, Bm, AtnL);
    // Wo + residual
    gemm_bf16<1><<<dim3(4, 32), 256, 0, stream>>>(
        AtnL, WoB, nullptr, Z, Z2, nullptr, nullptr, TOKc, 512, 512);
    // LN2
    ln_kernel<<<TOKc, 256, 0, stream>>>(Z2, g2, b2, Zn2);
    // MLP1
    gemm_bf16<2><<<dim3(16, 32), 256, 0, stream>>>(
        Zn2, Wp1B, bp1, nullptr, Hb, nullptr, nullptr, TOKc, 2048, 512);
    // MLP2 + residual
    gemm_bf16<3><<<dim3(4, 32), 256, 0, stream>>>(
        Hb, Wp2B, bp2, Z2, out, nullptr, nullptr, TOKc, 512, 2048);
}

// Round 3
// 282.435 us; speedup vs baseline: 3.4792x; 1.0881x over previous
//
#include <hip/hip_runtime.h>
#include <hip/hip_bf16.h>
#include <cstddef>
#include <cstdint>

#define Bv 4
#define Nv 1024
#define DM 512
#define Hh 8
#define DHv 64
#define TOKc 4096

typedef __attribute__((ext_vector_type(4))) float f32x4;
typedef __attribute__((ext_vector_type(8))) short s16x8;

__device__ __forceinline__ uint32_t f2bf_bits(float f) {
    uint32_t x = __float_as_uint(f);
    return (x + 0x7FFFu + ((x >> 16) & 1u)) >> 16;
}
__device__ __forceinline__ short f2bf(float f) { return (short)f2bf_bits(f); }
__device__ __forceinline__ float bf2f(short s) {
    return __uint_as_float(((uint32_t)(uint16_t)s) << 16);
}

__device__ __forceinline__ void g2lds16(const void* g, void* l) {
    __builtin_amdgcn_global_load_lds(
        (const __attribute__((address_space(1))) void*)g,
        (__attribute__((address_space(3))) void*)l, 16, 0, 0);
}

// ---------------------------------------------------------------------------
// all 4 weight tensors -> bf16, one launch
// sizes: Wqkv 786432, Wo 262144, Wp1 1048576, Wp2 1048576 (elements)
// ---------------------------------------------------------------------------
__global__ __launch_bounds__(256) void conv_all(
    const float* __restrict__ W0, const float* __restrict__ W1,
    const float* __restrict__ W2, const float* __restrict__ W3,
    short* __restrict__ D0, short* __restrict__ D1,
    short* __restrict__ D2, short* __restrict__ D3)
{
    int bid = blockIdx.x;
    const float* s; short* d; int base;
    if (bid < 768)       { s = W0; d = D0; base = bid * 1024; }
    else if (bid < 1024) { s = W1; d = D1; base = (bid - 768) * 1024; }
    else if (bid < 2048) { s = W2; d = D2; base = (bid - 1024) * 1024; }
    else                 { s = W3; d = D3; base = (bid - 2048) * 1024; }
    int i = base + threadIdx.x * 4;
    float4 v = *(const float4*)&s[i];
    short4 o = { f2bf(v.x), f2bf(v.y), f2bf(v.z), f2bf(v.w) };
    *(short4*)&d[i] = o;
}

// ---------------------------------------------------------------------------
// pack bias = new_mask - gamma*D (lo bf16) and mask (hi bf16) into u32
// ---------------------------------------------------------------------------
__global__ __launch_bounds__(256) void prep_bm(
    const float* __restrict__ Dm, const float* __restrict__ nm,
    const float* __restrict__ mk, const float* __restrict__ gamma,
    uint32_t* __restrict__ out)
{
    int i = (blockIdx.x * 256 + threadIdx.x) * 4;
    float g = gamma[0];
    float4 d = *(const float4*)&Dm[i];
    float4 n = *(const float4*)&nm[i];
    float4 m = *(const float4*)&mk[i];
    uint4 o;
    o.x = f2bf_bits(n.x - g * d.x) | (f2bf_bits(m.x) << 16);
    o.y = f2bf_bits(n.y - g * d.y) | (f2bf_bits(m.y) << 16);
    o.z = f2bf_bits(n.z - g * d.z) | (f2bf_bits(m.z) << 16);
    o.w = f2bf_bits(n.w - g * d.w) | (f2bf_bits(m.w) << 16);
    *(uint4*)&out[i] = o;
}

// ---------------------------------------------------------------------------
// LayerNorm -> bf16 out
// ---------------------------------------------------------------------------
__global__ __launch_bounds__(256) void ln_kernel(
    const float* __restrict__ X, const float* __restrict__ g,
    const float* __restrict__ bb, short* __restrict__ Y)
{
    __shared__ float red[8];
    int row = blockIdx.x, tid = threadIdx.x;
    const float* x = X + (size_t)row * DM;
    float v0 = x[tid], v1 = x[tid + 256];
    float s = v0 + v1, ss = v0 * v0 + v1 * v1;
#pragma unroll
    for (int o = 32; o > 0; o >>= 1) {
        s += __shfl_xor(s, o);
        ss += __shfl_xor(ss, o);
    }
    int lane = tid & 63, wid = tid >> 6;
    if (lane == 0) { red[wid] = s; red[4 + wid] = ss; }
    __syncthreads();
    float S = red[0] + red[1] + red[2] + red[3];
    float SS = red[4] + red[5] + red[6] + red[7];
    float mean = S * (1.f / DM);
    float var = SS * (1.f / DM) - mean * mean;
    float rstd = rsqrtf(var + 1e-5f);
    short* y = Y + (size_t)row * DM;
    y[tid]       = f2bf((v0 - mean) * rstd * g[tid]       + bb[tid]);
    y[tid + 256] = f2bf((v1 - mean) * rstd * g[tid + 256] + bb[tid + 256]);
}

// ---------------------------------------------------------------------------
// bf16 MFMA NT GEMM: C[M,N] = A[M,Ks] @ Bw[N,Ks]^T with row stride Kst.
// Tile BM x BN, BK=32, 4 waves in 2x2.
// EPI 0: +bias, scatter qkv -> Vt(b,h,d,n) / Q(b,h,n,d) / K(b,h,n,d)  bf16
// EPI 1: + resid -> fp32
// EPI 2: relu(+bias) -> bf16
// EPI 4: split-K partial -> bf16 at C0 + z*M*N (A,B advanced by z*Ks)
// ---------------------------------------------------------------------------
template <int EPI, int BM, int BN>
__global__ __launch_bounds__(256) void gemm_bf16(
    const short* __restrict__ A, const short* __restrict__ Bw,
    const float* __restrict__ bias, const float* __restrict__ resid,
    void* __restrict__ C0, short* __restrict__ C2, short* __restrict__ C3,
    int M, int N, int Ks, int Kst)
{
    constexpr int FI = BM / 32, FJ = BN / 32;
    __shared__ short As[BM * 32];
    __shared__ short Bs[BN * 32];
    int tid = threadIdx.x;
    int lane = tid & 63, wave = tid >> 6;
    int bm = blockIdx.y * BM, bn = blockIdx.x * BN;
    int wm = (wave >> 1) * (BM / 2), wn = (wave & 1) * (BN / 2);
    int n_lo = lane & 15, quad = lane >> 4;

    f32x4 acc[FI][FJ] = {};

    int koff = (EPI == 4) ? blockIdx.z * Ks : 0;
    int lrow = lane >> 2, lchunk = (lane & 3) * 8;
    const short* Ag = A + (size_t)(bm + wave * (BM / 4) + lrow) * Kst + koff + lchunk;
    const short* Bg = Bw + (size_t)(bn + wave * (BN / 4) + lrow) * Kst + koff + lchunk;

    for (int k0 = 0; k0 < Ks; k0 += 32) {
        __syncthreads();
#pragma unroll
        for (int r = 0; r < BM / 64; r++)
            g2lds16(Ag + (size_t)r * 16 * Kst + k0, &As[(wave * (BM / 4) + r * 16) * 32]);
#pragma unroll
        for (int r = 0; r < BN / 64; r++)
            g2lds16(Bg + (size_t)r * 16 * Kst + k0, &Bs[(wave * (BN / 4) + r * 16) * 32]);
        __syncthreads();
        s16x8 af[FI], bf[FJ];
#pragma unroll
        for (int i = 0; i < FI; i++)
            af[i] = *(const s16x8*)&As[(wm + i * 16 + n_lo) * 32 + quad * 8];
#pragma unroll
        for (int j = 0; j < FJ; j++)
            bf[j] = *(const s16x8*)&Bs[(wn + j * 16 + n_lo) * 32 + quad * 8];
#pragma unroll
        for (int i = 0; i < FI; i++)
#pragma unroll
            for (int j = 0; j < FJ; j++)
                acc[i][j] = __builtin_amdgcn_mfma_f32_16x16x32_bf16(
                    af[i], bf[j], acc[i][j], 0, 0, 0);
    }

#pragma unroll
    for (int i = 0; i < FI; i++) {
#pragma unroll
        for (int j = 0; j < FJ; j++) {
            int col = bn + wn + j * 16 + n_lo;
#pragma unroll
            for (int r = 0; r < 4; r++) {
                int m = bm + wm + i * 16 + quad * 4 + r;
                float v = acc[i][j][r];
                if (EPI == 0) {
                    v += bias[col];
                    int hh = col / 192;
                    int rr = col - hh * 192;
                    int part = rr >> 6, dd = rr & 63;
                    int bI = m >> 10, nI = m & 1023;
                    if (part == 0)
                        ((short*)C0)[((size_t)((bI * Hh + hh) * DHv + dd)) * Nv + nI] = f2bf(v);
                    else if (part == 1)
                        C2[((size_t)((bI * Hh + hh) * Nv + nI)) * DHv + dd] = f2bf(v);
                    else
                        C3[((size_t)((bI * Hh + hh) * Nv + nI)) * DHv + dd] = f2bf(v);
                } else if (EPI == 1) {
                    ((float*)C0)[(size_t)m * N + col] = v + resid[(size_t)m * N + col];
                } else if (EPI == 2) {
                    v += bias[col];
                    ((short*)C0)[(size_t)m * N + col] = f2bf(v > 0.f ? v : 0.f);
                } else {
                    ((short*)C0)[(size_t)blockIdx.z * M * N + (size_t)m * N + col] = f2bf(v);
                }
            }
        }
    }
}

// ---------------------------------------------------------------------------
// out = P0 + P1 + bias + resid   (MLP2 split-K combine), 2M floats
// ---------------------------------------------------------------------------
__global__ __launch_bounds__(256) void combine_mlp2(
    const short* __restrict__ P, const float* __restrict__ bias,
    const float* __restrict__ resid, float* __restrict__ out)
{
    int i = (blockIdx.x * 256 + threadIdx.x) * 4;
    float4 rz = *(const float4*)&resid[i];
    float4 bz = *(const float4*)&bias[i & 511];
    short4 p0 = *(const short4*)&P[i];
    short4 p1 = *(const short4*)&P[i + 2097152];
    float4 o;
    o.x = bf2f(p0.x) + bf2f(p1.x) + bz.x + rz.x;
    o.y = bf2f(p0.y) + bf2f(p1.y) + bz.y + rz.y;
    o.z = bf2f(p0.z) + bf2f(p1.z) + bz.z + rz.z;
    o.w = bf2f(p0.w) + bf2f(p1.w) + bz.w + rz.w;
    *(float4*)&out[i] = o;
}

// ---------------------------------------------------------------------------
// Flash attention, split-K: block = (b,h,q-tile of 16); wave w owns keys
// [w*256,(w+1)*256) with online softmax; merge (m,l,O) across waves in LDS.
// ---------------------------------------------------------------------------
__global__ __launch_bounds__(256) void attn_mfma(
    const short* __restrict__ Q, const short* __restrict__ K,
    const short* __restrict__ Vt, const uint32_t* __restrict__ Bm,
    short* __restrict__ attn_l)
{
    __shared__ short Pl[4][16][40];
    __shared__ float Osh[4][16][68];
    __shared__ float Msh[4][16];
    __shared__ float Lsh[4][16];

    int tid = threadIdx.x, lane = tid & 63, wave = tid >> 6;
    int n_lo = lane & 15, quad = lane >> 4;
    int q0 = blockIdx.x * 16;
    int b = blockIdx.y >> 3, h = blockIdx.y & 7;
    int kbase = wave * 256;

    const short* Qp = Q + ((size_t)((b * Hh + h) * Nv + q0)) * DHv;
    const short* Kp = K + ((size_t)((b * Hh + h) * Nv)) * DHv;
    const short* Vp = Vt + ((size_t)((b * Hh + h) * DHv)) * Nv;
    const uint32_t* Bp = Bm + ((size_t)(b * Nv + q0)) * Nv + kbase;

    s16x8 a0 = *(const s16x8*)&Qp[n_lo * DHv + quad * 8];
    s16x8 a1 = *(const s16x8*)&Qp[n_lo * DHv + 32 + quad * 8];

    f32x4 O[4] = {};
    float mo[4] = {-1e30f, -1e30f, -1e30f, -1e30f};
    float l[4] = {0.f, 0.f, 0.f, 0.f};

    for (int it = 0; it < 8; ++it) {
        int key0 = kbase + it * 32;
        s16x8 k0a = *(const s16x8*)&Kp[(size_t)(key0 + n_lo) * DHv + quad * 8];
        s16x8 k0b = *(const s16x8*)&Kp[(size_t)(key0 + n_lo) * DHv + 32 + quad * 8];
        s16x8 k1a = *(const s16x8*)&Kp[(size_t)(key0 + 16 + n_lo) * DHv + quad * 8];
        s16x8 k1b = *(const s16x8*)&Kp[(size_t)(key0 + 16 + n_lo) * DHv + 32 + quad * 8];
        f32x4 z = {0.f, 0.f, 0.f, 0.f};
        f32x4 s0 = __builtin_amdgcn_mfma_f32_16x16x32_bf16(
            a1, k0b, __builtin_amdgcn_mfma_f32_16x16x32_bf16(a0, k0a, z, 0, 0, 0), 0, 0, 0);
        f32x4 s1 = __builtin_amdgcn_mfma_f32_16x16x32_bf16(
            a1, k1b, __builtin_amdgcn_mfma_f32_16x16x32_bf16(a0, k1a, z, 0, 0, 0), 0, 0, 0);

        float mk0[4], mk1[4], mx[4];
#pragma unroll
        for (int i = 0; i < 4; i++) {
            uint32_t u0 = Bp[(size_t)(quad * 4 + i) * Nv + it * 32 + n_lo];
            uint32_t u1 = Bp[(size_t)(quad * 4 + i) * Nv + it * 32 + 16 + n_lo];
            s0[i] = s0[i] * 0.125f + __uint_as_float(u0 << 16);
            s1[i] = s1[i] * 0.125f + __uint_as_float(u1 << 16);
            mk0[i] = __uint_as_float(u0 & 0xFFFF0000u);
            mk1[i] = __uint_as_float(u1 & 0xFFFF0000u);
            mx[i] = fmaxf(s0[i], s1[i]);
        }
#pragma unroll
        for (int off = 1; off < 16; off <<= 1)
#pragma unroll
            for (int i = 0; i < 4; i++)
                mx[i] = fmaxf(mx[i], __shfl_xor(mx[i], off));

        float al[4], ls[4];
#pragma unroll
        for (int i = 0; i < 4; i++) {
            float mn = fmaxf(mo[i], mx[i]);
            al[i] = __expf(mo[i] - mn);
            mo[i] = mn;
            s0[i] = __expf(s0[i] - mn);
            s1[i] = __expf(s1[i] - mn);
            ls[i] = s0[i] + s1[i];
        }
#pragma unroll
        for (int off = 1; off < 16; off <<= 1)
#pragma unroll
            for (int i = 0; i < 4; i++)
                ls[i] += __shfl_xor(ls[i], off);
#pragma unroll
        for (int i = 0; i < 4; i++) {
            l[i] = l[i] * al[i] + ls[i];
            Pl[wave][quad * 4 + i][n_lo]      = f2bf(s0[i] * mk0[i]);
            Pl[wave][quad * 4 + i][16 + n_lo] = f2bf(s1[i] * mk1[i]);
        }
#pragma unroll
        for (int t = 0; t < 4; t++)
#pragma unroll
            for (int i = 0; i < 4; i++) O[t][i] *= al[i];

        s16x8 pa = *(const s16x8*)&Pl[wave][n_lo][quad * 8];
#pragma unroll
        for (int t = 0; t < 4; t++) {
            s16x8 vb = *(const s16x8*)&Vp[(size_t)(t * 16 + n_lo) * Nv + key0 + quad * 8];
            O[t] = __builtin_amdgcn_mfma_f32_16x16x32_bf16(pa, vb, O[t], 0, 0, 0);
        }
    }

    // ---- merge 4 wave-partials ----
    if (n_lo == 0) {
#pragma unroll
        for (int i = 0; i < 4; i++) Msh[wave][quad * 4 + i] = mo[i];
    }
    __syncthreads();
    float scale[4];
#pragma unroll
    for (int i = 0; i < 4; i++) {
        int r = quad * 4 + i;
        float ms = fmaxf(fmaxf(Msh[0][r], Msh[1][r]), fmaxf(Msh[2][r], Msh[3][r]));
        scale[i] = __expf(mo[i] - ms);
    }
    if (n_lo == 0) {
#pragma unroll
        for (int i = 0; i < 4; i++) Lsh[wave][quad * 4 + i] = l[i] * scale[i];
    }
#pragma unroll
    for (int t = 0; t < 4; t++)
#pragma unroll
        for (int i = 0; i < 4; i++)
            Osh[wave][quad * 4 + i][t * 16 + n_lo] = O[t][i] * scale[i];
    __syncthreads();

    int col = tid & 63, rb = (tid >> 6) * 4;
#pragma unroll
    for (int r = 0; r < 4; r++) {
        int row = rb + r;
        float s = Osh[0][row][col] + Osh[1][row][col] + Osh[2][row][col] + Osh[3][row][col];
        float lt = Lsh[0][row] + Lsh[1][row] + Lsh[2][row] + Lsh[3][row];
        float o = s / lt;
        o = o > 0.f ? o : 0.01f * o;
        attn_l[((size_t)(b * Nv + q0 + row)) * DM + h * DHv + col] = f2bf(o);
    }
}

// ---------------------------------------------------------------------------
extern "C" void kernel_launch(void* const* d_in, const int* in_sizes, int n_in,
                              void* d_out, int out_size, void* d_ws, size_t ws_size,
                              hipStream_t stream)
{
    const float* Z     = (const float*)d_in[0];
    const float* D     = (const float*)d_in[1];
    const float* nmsk  = (const float*)d_in[2];
    const float* msk   = (const float*)d_in[3];
    const float* Wqkv  = (const float*)d_in[4];
    const float* bqkv  = (const float*)d_in[5];
    const float* Wo    = (const float*)d_in[6];
    const float* g1    = (const float*)d_in[7];
    const float* b1    = (const float*)d_in[8];
    const float* g2    = (const float*)d_in[9];
    const float* b2    = (const float*)d_in[10];
    const float* Wp1   = (const float*)d_in[11];
    const float* bp1   = (const float*)d_in[12];
    const float* Wp2   = (const float*)d_in[13];
    const float* bp2   = (const float*)d_in[14];
    const float* gamma = (const float*)d_in[15];
    float* out = (float*)d_out;
    char* w = (char*)d_ws;

    const size_t MB = 1048576;
    short*    WqkvB = (short*)(w);                 // [0, 1.5M)
    short*    WoB   = (short*)(w + 1572864);       // [1.5M, 2M)
    short*    Wp1B  = (short*)(w + 2 * MB);        // [2M, 4M)
    short*    Wp2B  = (short*)(w + 4 * MB);        // [4M, 6M)
    float*    Z2    = (float*)(w + 6 * MB);        // [6M, 14M)
    uint32_t* Bm    = (uint32_t*)(w + 14 * MB);    // [14M, 30M)  dead after attn
    short*    Zn    = (short*)(w + 30 * MB);       // [30M, 34M)  dead after QKV
    short*    Qb    = (short*)(w + 34 * MB);       // [34M, 38M)
    short*    Kb    = (short*)(w + 38 * MB);       // [38M, 42M)
    short*    VtB   = (short*)(w + 42 * MB);       // [42M, 46M)  dead after attn
    short*    AtnL  = (short*)(w + 30 * MB);       // reuse Zn
    short*    Zn2   = (short*)(w + 14 * MB);       // reuse Bm head
    short*    Hb    = (short*)(w + 18 * MB);       // [18M, 34M)
    short*    Pp    = (short*)(w + 34 * MB);       // [34M, 42M) reuse Q/K (2x 4MB)

    conv_all<<<3072, 256, 0, stream>>>(Wqkv, Wo, Wp1, Wp2, WqkvB, WoB, Wp1B, Wp2B);
    prep_bm<<<4096, 256, 0, stream>>>(D, nmsk, msk, gamma, Bm);
    ln_kernel<<<TOKc, 256, 0, stream>>>(Z, g1, b1, Zn);
    // QKV: 4096x1536x512, 128x64 tiles -> 768 blocks
    gemm_bf16<0, 128, 64><<<dim3(24, 32), 256, 0, stream>>>(
        Zn, WqkvB, bqkv, nullptr, VtB, Qb, Kb, TOKc, 1536, 512, 512);
    // attention: 2048 blocks x 4 waves (split-K over keys)
    attn_mfma<<<dim3(64, 32), 256, 0, stream>>>(Qb, Kb, VtB, Bm, AtnL);
    // Wo + residual: 4096x512x512, 64x64 tiles -> 512 blocks
    gemm_bf16<1, 64, 64><<<dim3(8, 64), 256, 0, stream>>>(
        AtnL, WoB, nullptr, Z, Z2, nullptr, nullptr, TOKc, 512, 512, 512);
    ln_kernel<<<TOKc, 256, 0, stream>>>(Z2, g2, b2, Zn2);
    // MLP1: 4096x2048x512, 128x64 tiles -> 1024 blocks
    gemm_bf16<2, 128, 64><<<dim3(32, 32), 256, 0, stream>>>(
        Zn2, Wp1B, bp1, nullptr, Hb, nullptr, nullptr, TOKc, 2048, 512, 512);
    // MLP2 split-K=2: 4096x512x(2x1024), 128x64 tiles -> 512 blocks
    gemm_bf16<4, 128, 64><<<dim3(8, 32, 2), 256, 0, stream>>>(
        Hb, Wp2B, nullptr, nullptr, Pp, nullptr, nullptr, TOKc, 512, 1024, 2048);
    combine_mlp2<<<2048, 256, 0, stream>>>(Pp, bp2, Z2, out);
}